// Round 1
// baseline (294.147 us; speedup 1.0000x reference)
//
#include <hip/hip_runtime.h>

// Problem constants (B, P, E, S) = (4, 2048, 4096, 16)
#define BB 4
#define PP 2048
#define EE 4096
#define SS 16

static __device__ __forceinline__ float fast_exp2(float x) {
#if __has_builtin(__builtin_amdgcn_exp2f)
    return __builtin_amdgcn_exp2f(x);
#else
    return exp2f(x);
#endif
}

// tanh(x) = (e^{2x}-1)/(e^{2x}+1) = (t-1)/(t+1), t = 2^{2*log2(e)*x}
// clamp |x|<=9: exp2 arg <= 26 (no overflow), tanh(9) = 1 - 3e-8 -> exact enough
static __device__ __forceinline__ float fast_tanh(float x) {
    float xc = fminf(fmaxf(x, -9.0f), 9.0f);
    float t  = fast_exp2(xc * 2.885390081777927f);   // 2*log2(e)
    return (t - 1.0f) * __builtin_amdgcn_rcpf(t + 1.0f);
}

// Kernel 1: a[p][j] = sum_k product[p][k]*W1[k][j]   (Wa = W1 rows 0..15)
//           b[e][j] = sum_k person[e][k]*W1[16+k][j] (Wb = W1 rows 16..31)
// 6144 rows total, one thread per row. Trivial cost.
__global__ __launch_bounds__(256) void precompute_ab(
    const float* __restrict__ product, const float* __restrict__ person,
    const float* __restrict__ W1, float* __restrict__ a, float* __restrict__ b)
{
    int row = blockIdx.x * blockDim.x + threadIdx.x;
    if (row >= PP + EE) return;
    const bool  is_p  = row < PP;
    const float* in   = is_p ? (product + (size_t)row * SS)
                             : (person  + (size_t)(row - PP) * SS);
    const float* W    = is_p ? W1 : (W1 + SS * SS);
    float*       orow = is_p ? (a + (size_t)row * SS)
                             : (b + (size_t)(row - PP) * SS);
    float v[SS];
#pragma unroll
    for (int k = 0; k < SS; ++k) v[k] = in[k];
#pragma unroll
    for (int j = 0; j < SS; ++j) {
        float acc = 0.0f;
#pragma unroll
        for (int k = 0; k < SS; ++k) acc = fmaf(v[k], W[k * SS + j], acc);
        orow[j] = acc;
    }
}

// Kernel 2: one thread per (p,e) pair. Block = 256 consecutive e, fixed p.
// a[p][*] and W2/W3 are wave-uniform -> expect s_load scalarization.
__global__ __launch_bounds__(256) void score_mul(
    const float* __restrict__ x, const float* __restrict__ a,
    const float* __restrict__ b, const float* __restrict__ W2,
    const float* __restrict__ W3, float* __restrict__ out)
{
    const int p = blockIdx.y;
    const int e = blockIdx.x * 256 + threadIdx.x;

    // b row: 64 B per thread, vectorized (L2-resident, 256 KB table)
    const float4* brow = (const float4*)(b + (size_t)e * SS);
    float4 b0 = brow[0], b1 = brow[1], b2 = brow[2], b3 = brow[3];
    float br[SS] = {b0.x,b0.y,b0.z,b0.w, b1.x,b1.y,b1.z,b1.w,
                    b2.x,b2.y,b2.z,b2.w, b3.x,b3.y,b3.z,b3.w};

    // h1 = tanh(a[p] + b[e])   (a[p][s] uniform -> SGPR)
    float h1[SS];
#pragma unroll
    for (int s = 0; s < SS; ++s) h1[s] = fast_tanh(a[(size_t)p * SS + s] + br[s]);

    // h2pre = h1 @ W2 : 256 FMA, W2[s][j] uniform -> SGPR operand FMAs
    float acc[SS];
#pragma unroll
    for (int j = 0; j < SS; ++j) acc[j] = 0.0f;
#pragma unroll
    for (int s = 0; s < SS; ++s) {
#pragma unroll
        for (int j = 0; j < SS; ++j)
            acc[j] = fmaf(h1[s], W2[s * SS + j], acc[j]);
    }

    // z = tanh(h2pre) . W3 ; leaky relu
    float z = 0.0f;
#pragma unroll
    for (int j = 0; j < SS; ++j) z = fmaf(fast_tanh(acc[j]), W3[j], z);
    float score = (z >= 0.0f) ? z : 0.1f * z;

    // out[bb][p][e] = score * x[bb][p][e]
    const size_t base = (size_t)p * EE + (size_t)e;
#pragma unroll
    for (int bb = 0; bb < BB; ++bb) {
        const size_t idx = (size_t)bb * ((size_t)PP * EE) + base;
        out[idx] = score * x[idx];
    }
}

extern "C" void kernel_launch(void* const* d_in, const int* in_sizes, int n_in,
                              void* d_out, int out_size, void* d_ws, size_t ws_size,
                              hipStream_t stream)
{
    const float* x       = (const float*)d_in[0];
    const float* product = (const float*)d_in[1];
    const float* person  = (const float*)d_in[2];
    const float* W1      = (const float*)d_in[3];
    const float* W2      = (const float*)d_in[4];
    const float* W3      = (const float*)d_in[5];
    float* out = (float*)d_out;

    // workspace: a = PP*SS floats, b = EE*SS floats (393 KB total)
    float* a = (float*)d_ws;
    float* b = a + (size_t)PP * SS;

    dim3 g1((PP + EE + 255) / 256);
    precompute_ab<<<g1, 256, 0, stream>>>(product, person, W1, a, b);

    dim3 g2(EE / 256, PP);
    score_mul<<<g2, 256, 0, stream>>>(x, a, b, W2, W3, out);
}

// Round 2
// 266.805 us; speedup vs baseline: 1.1025x; 1.1025x over previous
//
#include <hip/hip_runtime.h>

// (B, P, E, S) = (4, 2048, 4096, 16)
#define BB 4
#define PP 2048
#define EE 4096
#define SS 16
#define TP 16      // p-values per block iteration loop
#define EBLK 256   // e per block = 4 waves x 64 lanes

typedef __fp16 v2h __attribute__((ext_vector_type(2)));
typedef __fp16 v4h __attribute__((ext_vector_type(4)));
typedef float  v4f __attribute__((ext_vector_type(4)));

static __device__ __forceinline__ float fast_tanh(float x) {
    // tanh(x) = (t-1)/(t+1), t = 2^(2*log2(e)*x), clamp |x|<=9
    float xc = fminf(fmaxf(x, -9.0f), 9.0f);
    float t  = __builtin_amdgcn_exp2f(xc * 2.885390081777927f);
    return (t - 1.0f) * __builtin_amdgcn_rcpf(t + 1.0f);
}

// a[p][j] = sum_k product[p][k]*W1[k][j] ; b[e][j] = sum_k person[e][k]*W1[16+k][j]
__global__ __launch_bounds__(256) void precompute_ab(
    const float* __restrict__ product, const float* __restrict__ person,
    const float* __restrict__ W1, float* __restrict__ a, float* __restrict__ b)
{
    int row = blockIdx.x * blockDim.x + threadIdx.x;
    if (row >= PP + EE) return;
    const bool  is_p  = row < PP;
    const float* in   = is_p ? (product + (size_t)row * SS)
                             : (person  + (size_t)(row - PP) * SS);
    const float* W    = is_p ? W1 : (W1 + SS * SS);
    float*       orow = is_p ? (a + (size_t)row * SS)
                             : (b + (size_t)(row - PP) * SS);
    float v[SS];
#pragma unroll
    for (int k = 0; k < SS; ++k) v[k] = in[k];
#pragma unroll
    for (int j = 0; j < SS; ++j) {
        float acc = 0.0f;
#pragma unroll
        for (int k = 0; k < SS; ++k) acc = fmaf(v[k], W[k * SS + j], acc);
        orow[j] = acc;
    }
}

// One lane per (p,e) pair; h1@W2 via mfma_f32_16x16x16_f16 as C = W2^T @ h1^T.
// C layout (col=lane&15=pair, row=(lane>>4)*4+reg=j) => per-lane j-partials,
// 2-stage shfl_xor reduce over lane>>4, score for pair L = pg[L>>4].
__global__ __launch_bounds__(256, 4) void score_mul(
    const float* __restrict__ x, const float* __restrict__ a,
    const float* __restrict__ b, const float* __restrict__ W2,
    const float* __restrict__ W3, float* __restrict__ out)
{
    const int tid  = threadIdx.x;
    const int lane = tid & 63;
    const int wv   = tid >> 6;
    const int n    = lane & 15;   // MFMA col: pair-within-group / A-row j
    const int q    = lane >> 4;   // quad: k-block / C row-block

    const int e  = blockIdx.x * EBLK + tid;
    const int p0 = blockIdx.y * TP;

    // wave-private h1 staging: [wave][pair][8 x half2] = 8 KB
    __shared__ int h1s[4][64][8];

    // my pair's b-row (16 floats, L2-resident table)
    float br[SS];
    {
        const float4* brp = (const float4*)(b + (size_t)e * SS);
#pragma unroll
        for (int i = 0; i < 4; ++i) {
            float4 t = brp[i];
            br[4*i+0]=t.x; br[4*i+1]=t.y; br[4*i+2]=t.z; br[4*i+3]=t.w;
        }
    }

    // A-frag (constant): A[m=j=n][k=s=q*4+i] = W2[s][j]
    v4h w2a;
    {
        float c0 = W2[(q*4+0)*SS + n];
        float c1 = W2[(q*4+1)*SS + n];
        float c2 = W2[(q*4+2)*SS + n];
        float c3 = W2[(q*4+3)*SS + n];
        v2h lo = __builtin_amdgcn_cvt_pkrtz(c0, c1);
        v2h hi = __builtin_amdgcn_cvt_pkrtz(c2, c3);
        w2a[0]=lo[0]; w2a[1]=lo[1]; w2a[2]=hi[0]; w2a[3]=hi[1];
    }

    // W3 fragment: w3r[r] = W3[q*4+r]
    float4 w3v = ((const float4*)W3)[q];
    const float w3r[4] = {w3v.x, w3v.y, w3v.z, w3v.w};

    for (int ip = 0; ip < TP; ++ip) {
        const int p = p0 + ip;
        const size_t base = (size_t)p * EE + (size_t)e;

        // prefetch x early (independent of score computation)
        float xv[BB];
#pragma unroll
        for (int bb2 = 0; bb2 < BB; ++bb2)
            xv[bb2] = x[(size_t)bb2 * ((size_t)PP * EE) + base];

        // h1 = tanh(a[p] + b[e]); pack to f16 pairs
        const float* __restrict__ ap = a + (size_t)p * SS;  // uniform -> s_load
        int hp[8];
#pragma unroll
        for (int r = 0; r < 8; ++r) {
            float t0 = fast_tanh(ap[2*r+0] + br[2*r+0]);
            float t1 = fast_tanh(ap[2*r+1] + br[2*r+1]);
            hp[r] = __builtin_bit_cast(int, __builtin_amdgcn_cvt_pkrtz(t0, t1));
        }

        // stage my pair's h1 row (32 B). Wave-private region: DS ops of a
        // wave execute in order, no __syncthreads needed.
        int* myrow = &h1s[wv][lane][0];
        *(int4*)(myrow + 0) = make_int4(hp[0], hp[1], hp[2], hp[3]);
        *(int4*)(myrow + 4) = make_int4(hp[4], hp[5], hp[6], hp[7]);
        __builtin_amdgcn_wave_barrier();

        // 4 MFMAs: group g covers pairs g*16..g*16+15
        v4f acc[4];
#pragma unroll
        for (int g = 0; g < 4; ++g) {
            int2 rb = *(const int2*)&h1s[wv][g*16 + n][q*2];
            v4h bfrag = __builtin_bit_cast(v4h, rb);
            v4f z4 = {0.f, 0.f, 0.f, 0.f};
            acc[g] = __builtin_amdgcn_mfma_f32_16x16x16f16(w2a, bfrag, z4, 0, 0, 0);
        }

        // z[pair] = sum_j tanh(h2pre[pair][j]) * W3[j]
        float pg[4];
#pragma unroll
        for (int g = 0; g < 4; ++g) {
            float s = 0.f;
#pragma unroll
            for (int r = 0; r < 4; ++r)
                s = fmaf(fast_tanh(acc[g][r]), w3r[r], s);
            s += __shfl_xor(s, 16);
            s += __shfl_xor(s, 32);
            pg[g] = s;
        }
        // my pair is L = q*16+n -> its z sits in pg[q]
        float s01 = (q & 1) ? pg[1] : pg[0];
        float s23 = (q & 1) ? pg[3] : pg[2];
        float z   = (q & 2) ? s23 : s01;
        float sc  = fmaxf(z, 0.f) + 0.1f * fminf(z, 0.f);  // leaky relu

#pragma unroll
        for (int bb2 = 0; bb2 < BB; ++bb2)
            out[(size_t)bb2 * ((size_t)PP * EE) + base] = sc * xv[bb2];
    }
}

extern "C" void kernel_launch(void* const* d_in, const int* in_sizes, int n_in,
                              void* d_out, int out_size, void* d_ws, size_t ws_size,
                              hipStream_t stream)
{
    const float* x       = (const float*)d_in[0];
    const float* product = (const float*)d_in[1];
    const float* person  = (const float*)d_in[2];
    const float* W1      = (const float*)d_in[3];
    const float* W2      = (const float*)d_in[4];
    const float* W3      = (const float*)d_in[5];
    float* out = (float*)d_out;

    float* a = (float*)d_ws;                  // PP*SS floats
    float* b = a + (size_t)PP * SS;           // EE*SS floats

    dim3 g1((PP + EE + 255) / 256);
    precompute_ab<<<g1, 256, 0, stream>>>(product, person, W1, a, b);

    dim3 g2(EE / EBLK, PP / TP);              // 16 x 128 = 2048 blocks
    score_mul<<<g2, 256, 0, stream>>>(x, a, b, W2, W3, out);
}

// Round 3
// 266.436 us; speedup vs baseline: 1.1040x; 1.0014x over previous
//
#include <hip/hip_runtime.h>

// (B, P, E, S) = (4, 2048, 4096, 16)
#define BB 4
#define PP 2048
#define EE 4096
#define SS 16
#define TP 16      // p-values per block
#define EBLK 256   // e per block = 4 waves x 64 lanes

typedef __fp16 v2h __attribute__((ext_vector_type(2)));
typedef __fp16 v4h __attribute__((ext_vector_type(4)));
typedef float  v4f __attribute__((ext_vector_type(4)));

// tanh(x) = 1 - 2/(exp2(2*log2e*x)+1). No clamp needed:
//   x->+inf: t=inf, rcp(inf)=0 -> 1 ; x->-inf: t=0, 1-2*rcp(1) = -1.
static __device__ __forceinline__ float fast_tanh(float x) {
    float t = __builtin_amdgcn_exp2f(x * 2.885390081777927f);
    return fmaf(-2.0f, __builtin_amdgcn_rcpf(t + 1.0f), 1.0f);
}

// a[p][j] = sum_k product[p][k]*W1[k][j] ; b[e][j] = sum_k person[e][k]*W1[16+k][j]
__global__ __launch_bounds__(256) void precompute_ab(
    const float* __restrict__ product, const float* __restrict__ person,
    const float* __restrict__ W1, float* __restrict__ a, float* __restrict__ b)
{
    int row = blockIdx.x * blockDim.x + threadIdx.x;
    if (row >= PP + EE) return;
    const bool  is_p  = row < PP;
    const float* in   = is_p ? (product + (size_t)row * SS)
                             : (person  + (size_t)(row - PP) * SS);
    const float* W    = is_p ? W1 : (W1 + SS * SS);
    float*       orow = is_p ? (a + (size_t)row * SS)
                             : (b + (size_t)(row - PP) * SS);
    float v[SS];
#pragma unroll
    for (int k = 0; k < SS; ++k) v[k] = in[k];
#pragma unroll
    for (int j = 0; j < SS; ++j) {
        float acc = 0.0f;
#pragma unroll
        for (int k = 0; k < SS; ++k) acc = fmaf(v[k], W[k * SS + j], acc);
        orow[j] = acc;
    }
}

// h1@W2 via mfma_f32_16x16x16_f16 as C = W2^T @ h1^T.
// Each lane computes its 4 B-fragments DIRECTLY (no LDS transpose):
//   bfrag[g][i] = h1[pair=g*16+n][s=q*4+i] = tanh(a[p][q*4+i] + b[eg][q*4+i])
// C layout (col=n=pair-in-group, row=q*4+r=j) -> per-lane j-partials,
// shfl_xor(16,32) reduce, score for own pair L sits in pg[L>>4].
__global__ __launch_bounds__(256) void score_mul(
    const float* __restrict__ x, const float* __restrict__ a,
    const float* __restrict__ b, const float* __restrict__ W2,
    const float* __restrict__ W3, float* __restrict__ out)
{
    const int tid  = threadIdx.x;
    const int lane = tid & 63;
    const int n    = lane & 15;   // MFMA col
    const int q    = lane >> 4;   // quad -> k/row block

    const int eown = blockIdx.x * EBLK + tid;            // my output pair's e
    const int ebase = blockIdx.x * EBLK + (tid & ~63);   // wave's first e
    const int p0 = blockIdx.y * TP;

    // b fragments (p-independent, L2-resident): brg[g][i] = b[ebase+g*16+n][q*4+i]
    float4 brg[4];
#pragma unroll
    for (int g = 0; g < 4; ++g)
        brg[g] = *(const float4*)(b + (size_t)(ebase + g*16 + n) * SS + q*4);

    // A-frag (constant): A[m=j=n][k=s=q*4+i] = W2[s][j]
    v4h w2a;
    {
        v2h lo = __builtin_amdgcn_cvt_pkrtz(W2[(q*4+0)*SS + n], W2[(q*4+1)*SS + n]);
        v2h hi = __builtin_amdgcn_cvt_pkrtz(W2[(q*4+2)*SS + n], W2[(q*4+3)*SS + n]);
        w2a[0]=lo[0]; w2a[1]=lo[1]; w2a[2]=hi[0]; w2a[3]=hi[1];
    }

    // W3 fragment: w3r[r] = W3[q*4+r]
    float4 w3v = ((const float4*)W3)[q];
    const float w3r[4] = {w3v.x, w3v.y, w3v.z, w3v.w};

    // per-plane x/out pointers for my pair
    size_t base0 = (size_t)p0 * EE + (size_t)eown;
    const float* __restrict__ xp0 = x   + base0;
    float*       __restrict__ op0 = out + base0;

    for (int ip = 0; ip < TP; ++ip) {
        const int p = p0 + ip;
        const size_t off = (size_t)ip * EE;

        // prefetch x (independent of score)
        float xv[BB];
#pragma unroll
        for (int bb2 = 0; bb2 < BB; ++bb2)
            xv[bb2] = xp0[(size_t)bb2 * ((size_t)PP * EE) + off];

        // a[p][q*4..+3]: one 64B cache line per p, broadcast across wave
        float4 av = *(const float4*)(a + (size_t)p * SS + q*4);

        // h1 directly in B-frag layout + pack to f16
        v4h bfrag[4];
#pragma unroll
        for (int g = 0; g < 4; ++g) {
            float t0 = fast_tanh(av.x + brg[g].x);
            float t1 = fast_tanh(av.y + brg[g].y);
            float t2 = fast_tanh(av.z + brg[g].z);
            float t3 = fast_tanh(av.w + brg[g].w);
            v2h lo = __builtin_amdgcn_cvt_pkrtz(t0, t1);
            v2h hi = __builtin_amdgcn_cvt_pkrtz(t2, t3);
            bfrag[g][0]=lo[0]; bfrag[g][1]=lo[1]; bfrag[g][2]=hi[0]; bfrag[g][3]=hi[1];
        }

        // z[pair] = sum_j tanh(h2pre[pair][j]) * W3[j]
        float pg[4];
#pragma unroll
        for (int g = 0; g < 4; ++g) {
            v4f z4 = {0.f, 0.f, 0.f, 0.f};
            v4f acc = __builtin_amdgcn_mfma_f32_16x16x16f16(w2a, bfrag[g], z4, 0, 0, 0);
            float s = 0.f;
#pragma unroll
            for (int r = 0; r < 4; ++r)
                s = fmaf(fast_tanh(acc[r]), w3r[r], s);
            s += __shfl_xor(s, 16);
            s += __shfl_xor(s, 32);
            pg[g] = s;
        }
        // my pair is lane L = q*16+n -> z sits in pg[q]
        float s01 = (q & 1) ? pg[1] : pg[0];
        float s23 = (q & 1) ? pg[3] : pg[2];
        float z   = (q & 2) ? s23 : s01;
        float sc  = fmaxf(z, 0.f) + 0.1f * fminf(z, 0.f);  // leaky relu

#pragma unroll
        for (int bb2 = 0; bb2 < BB; ++bb2)
            op0[(size_t)bb2 * ((size_t)PP * EE) + off] = sc * xv[bb2];
    }
}

extern "C" void kernel_launch(void* const* d_in, const int* in_sizes, int n_in,
                              void* d_out, int out_size, void* d_ws, size_t ws_size,
                              hipStream_t stream)
{
    const float* x       = (const float*)d_in[0];
    const float* product = (const float*)d_in[1];
    const float* person  = (const float*)d_in[2];
    const float* W1      = (const float*)d_in[3];
    const float* W2      = (const float*)d_in[4];
    const float* W3      = (const float*)d_in[5];
    float* out = (float*)d_out;

    float* a = (float*)d_ws;                  // PP*SS floats
    float* b = a + (size_t)PP * SS;           // EE*SS floats

    dim3 g1((PP + EE + 255) / 256);
    precompute_ab<<<g1, 256, 0, stream>>>(product, person, W1, a, b);

    dim3 g2(EE / EBLK, PP / TP);              // 16 x 128 = 2048 blocks
    score_mul<<<g2, 256, 0, stream>>>(x, a, b, W2, W3, out);
}